// Round 2
// baseline (279.621 us; speedup 1.0000x reference)
//
#include <hip/hip_runtime.h>
#include <hip/hip_bf16.h>

#define N_NODES 100000
#define N_EDGES 1000000
#define CH 128
#define KTOT 256
#define NCLS 3

#define NBKT 196                    // coarse buckets: dst>>9
#define EPB 4096                    // edges per partition block (parallelism!)
#define NB_A ((N_EDGES + EPB - 1) / EPB)          // 245
#define M_H (NBKT * NB_A)                          // 48020
#define NB_SCAN ((M_H + 1023) / 1024)              // 47 co-resident blocks

#define NB_CVTX (N_NODES * CH / 4 / 256)           // 12500
#define NB_CVTW (KTOT * CH / 256)                  // 128
#define NB_A1 (NB_A + NB_CVTX + 2 * NB_CVTW)       // 13001

typedef __attribute__((ext_vector_type(8))) short v8s;   // 8 bf16 (A/B frag)
typedef __attribute__((ext_vector_type(4))) float v4f;   // 4 f32 (C/D frag)

__device__ __forceinline__ float bf2f(unsigned short u) {
    return __uint_as_float(((unsigned int)u) << 16);
}

__device__ __forceinline__ unsigned short f2bf(float f) {  // RNE
    unsigned int u = __float_as_uint(f);
    unsigned int r = (u + 0x7fffu + ((u >> 16) & 1u)) >> 16;
    return (unsigned short)r;
}

__device__ __forceinline__ int edge_at(const void* e, int is64, long long i) {
    if (is64) return (int)((const long long*)e)[i];
    return ((const int*)e)[i];
}

__device__ __forceinline__ float ldf(const void* p, int isbf, size_t i) {
    if (isbf) return bf2f(((const unsigned short*)p)[i]);
    return ((const float*)p)[i];
}

__device__ __forceinline__ void acc_u32(unsigned int u, float& a0, float& a1) {
    a0 += bf2f((unsigned short)(u & 0xffffu));
    a1 += bf2f((unsigned short)(u >> 16));
}

// --- K0: dtype sniffers + done flag ---
__global__ void k_init(const void* __restrict__ e, const unsigned int* __restrict__ x,
                       int* __restrict__ eflag, int* __restrict__ dtf,
                       int* __restrict__ done) {
    if (blockIdx.x == 0) {
        if (threadIdx.x < 64) {
            int v = ((const int*)e)[2 * threadIdx.x + 1];
            unsigned long long bl = __ballot(v != 0);
            if (threadIdx.x == 0) *eflag = (bl == 0ULL) ? 1 : 0;
        } else if (threadIdx.x == 64) {
            *done = 0;
        }
    } else {
        if (threadIdx.x < 64) {
            unsigned int u = x[threadIdx.x];
            int ex = (u >> 7) & 0xff;
            int sane = (ex == 0) || (ex >= 100 && ex <= 154);
            unsigned long long bl = __ballot(sane);
            if (threadIdx.x == 0) *dtf = (__popcll(bl) >= 48) ? 1 : 0;
        }
    }
}

// --- K1: coarse-bucket histogram (LDS atomics only) interleaved with cvt.
// r(this): x converts to a DENSE [N][128] bf16 buffer (stride 128, no more
// 256-wide A rows — the mean half never touches global anymore). ---
__global__ void k_A1(const void* __restrict__ e, const int* __restrict__ eflag,
                     const int* __restrict__ dtf, int* __restrict__ hist,
                     const void* __restrict__ x, unsigned short* __restrict__ Xb,
                     const void* __restrict__ wl1, const void* __restrict__ wr1,
                     unsigned short* __restrict__ WT1,
                     const void* __restrict__ wl2, const void* __restrict__ wr2,
                     unsigned short* __restrict__ WT2) {
    int b = blockIdx.x;
    int t = threadIdx.x;
    if (b < NB_A) {
        __shared__ int h[NBKT];
        if (t < NBKT) h[t] = 0;
        __syncthreads();
        int is64 = *eflag;
#pragma unroll
        for (int j = 0; j < EPB / 256; j++) {
            int i = b * EPB + j * 256 + t;
            if (i < N_EDGES) {
                int dst = edge_at(e, is64, (long long)N_EDGES + i);
                atomicAdd(&h[dst >> 9], 1);
            }
        }
        __syncthreads();
        if (t < NBKT) hist[t * NB_A + b] = h[t];
    } else {
        int ob = b - NB_A;
        if (ob < NB_CVTX) {
            int idx = ob * 256 + t;
            int node = idx >> 5;
            int ch = (idx & 31) * 4;
            int isbf = *dtf;
            unsigned short o[4];
            if (isbf) {
                ushort4 u = *(const ushort4*)((const unsigned short*)x +
                                              (size_t)node * CH + ch);
                o[0] = u.x; o[1] = u.y; o[2] = u.z; o[3] = u.w;
            } else {
                float4 v = *(const float4*)((const float*)x + (size_t)node * CH + ch);
                o[0] = f2bf(v.x); o[1] = f2bf(v.y); o[2] = f2bf(v.z); o[3] = f2bf(v.w);
            }
            *(ushort4*)(Xb + (size_t)node * CH + ch) =
                make_ushort4(o[0], o[1], o[2], o[3]);
        } else {
            int rel = ob - NB_CVTX;
            const void* wl = (rel < NB_CVTW) ? wl1 : wl2;
            const void* wr = (rel < NB_CVTW) ? wr1 : wr2;
            unsigned short* WT = (rel < NB_CVTW) ? WT1 : WT2;
            int i = (rel % NB_CVTW) * 256 + t;
            int k = i >> 7;
            int n = i & 127;
            int isbf = *dtf;
            float v = (k < CH) ? ldf(wl, isbf, (size_t)k * CH + n)
                               : ldf(wr, isbf, (size_t)(k - CH) * CH + n);
            WT[(size_t)n * KTOT + k] = f2bf(v);
        }
    }
}

// --- K2: multi-block exclusive scan, producer-only spin barrier (r10 pattern:
// safe because EVERY spinning block is also a producer) ---
__global__ __launch_bounds__(1024) void k_scanH(int* __restrict__ hist,
                                                int* __restrict__ bsum,
                                                int* __restrict__ done) {
    __shared__ int s[1024];
    __shared__ int pre_sh;
    int t = threadIdx.x, b = blockIdx.x;
    int idx = b * 1024 + t;
    int v = (idx < M_H) ? hist[idx] : 0;
    s[t] = v;
    __syncthreads();
    for (int off = 1; off < 1024; off <<= 1) {
        int u = (t >= off) ? s[t - off] : 0;
        __syncthreads();
        s[t] += u;
        __syncthreads();
    }
    if (t == 1023) {
        bsum[b] = s[t];
        __threadfence();
        atomicAdd(done, 1);
    }
    if (t == 0) {
        while (__hip_atomic_load(done, __ATOMIC_ACQUIRE,
                                 __HIP_MEMORY_SCOPE_AGENT) < NB_SCAN) {
        }
        __threadfence();
        int run = 0;
        for (int r = 0; r < b; r++) run += bsum[r];
        pre_sh = run;
    }
    __syncthreads();
    if (idx < M_H) hist[idx] = s[t] - v + pre_sh;  // exclusive
}

// --- K3: partition scatter via LDS cursors; pack (src<<9)|(dst&511) ---
__global__ void k_A3(const void* __restrict__ e, const int* __restrict__ eflag,
                     const int* __restrict__ hist, unsigned int* __restrict__ part) {
    __shared__ int cur[NBKT];
    int b = blockIdx.x;
    int t = threadIdx.x;
    if (t < NBKT) cur[t] = hist[t * NB_A + b];
    __syncthreads();
    int is64 = *eflag;
#pragma unroll
    for (int j = 0; j < EPB / 256; j++) {
        int i = b * EPB + j * 256 + t;
        if (i < N_EDGES) {
            int src = edge_at(e, is64, i);
            int dst = edge_at(e, is64, (long long)N_EDGES + i);
            int pos = atomicAdd(&cur[dst >> 9], 1);  // LDS atomic
            part[pos] = ((unsigned int)src << 9) | (unsigned int)(dst & 511);
        }
    }
}

// --- K4: per-bucket finalize: degree count + scan -> row_start + csr_src ---
__global__ __launch_bounds__(1024) void k_B(const int* __restrict__ hist,
                                            const unsigned int* __restrict__ part,
                                            int* __restrict__ row_start,
                                            int* __restrict__ csr_src) {
    __shared__ int dcnt[512], sa[512], curs[512];
    int b = blockIdx.x;
    int t = threadIdx.x;
    int e0 = hist[b * NB_A];
    int e1 = (b + 1 < NBKT) ? hist[(b + 1) * NB_A] : N_EDGES;
    if (t < 512) dcnt[t] = 0;
    __syncthreads();
    for (int i = e0 + t; i < e1; i += 1024)
        atomicAdd(&dcnt[part[i] & 511], 1);
    __syncthreads();
    if (t < 512) sa[t] = dcnt[t];
    __syncthreads();
    for (int off = 1; off < 512; off <<= 1) {
        int v = 0;
        if (t < 512 && t >= off) v = sa[t - off];
        __syncthreads();
        if (t < 512) sa[t] += v;
        __syncthreads();
    }
    if (t < 512) {
        int excl = sa[t] - dcnt[t];
        curs[t] = e0 + excl;
        int node = b * 512 + t;
        if (node < N_NODES) row_start[node] = e0 + excl;
    }
    if (b == 0 && t == 0) row_start[N_NODES] = N_EDGES;
    __syncthreads();
    for (int i = e0 + t; i < e1; i += 1024) {
        unsigned int p = part[i];
        int pos = atomicAdd(&curs[p & 511], 1);  // LDS atomic
        csr_src[pos] = (int)(p >> 9);
    }
}

// --- FUSED gather-mean + MFMA GEMM + optional classifier epilogue.
// Phase 1: 256 thr = 16 nodes x 16 lanes per pass, 8 passes -> mean tile in
// LDS Am[128][LDA] (cols 0-127 of the A operand). Never touches global.
// Phase 2: K-loop k=0..7; k<4 A-frags from Am, k>=4 A-frags = root rows
// staged from the SAME src buffer (dbuf, as before). B staged per step.
// Gather is chip-level service-rate-bound, so issuing it from 8 waves/CU
// (2 blocks/CU) sustains the same rate while the co-resident block's MFMA
// overlaps it. Saves 51 MB/layer (mean write+re-read) and 2 launches. ---
#define LDK 40
#define LDA 136
#define CLS_LD 130
__global__ __launch_bounds__(256) void k_gemm_fused(
    const int* __restrict__ row_start, const int* __restrict__ csr_src,
    const unsigned short* __restrict__ src,    // [N][CH] bf16 (x or h1)
    const unsigned short* __restrict__ WT, const void* __restrict__ bias,
    const int* __restrict__ dtf,
    unsigned short* __restrict__ out,          // [N][CH] bf16 (h) or null
    const void* __restrict__ wcls, const void* __restrict__ bcls,
    float* __restrict__ cls_out) {
    __shared__ unsigned short smem[4 * 128 * LDK];   // As dbuf + Bs dbuf
    __shared__ unsigned short Am[128 * LDA];         // gathered mean tile
    __shared__ float wcls_s[CH * NCLS];
    unsigned short* As = smem;
    unsigned short* Bs = smem + 2 * 128 * LDK;
    const int t = threadIdx.x;
    const int w = t >> 6, l = t & 63;
    const int wx = w & 1, wy = w >> 1;
    const int quad = l >> 4, lrow = l & 15;
    const int row0 = blockIdx.x * 128;
    const int srow = t >> 1, shalf = t & 1;
    const int isbf = *dtf;

    if (cls_out) {
        for (int i = t; i < CH * NCLS; i += 256) wcls_s[i] = ldf(wcls, isbf, i);
    }

    // ---- phase 1: gather-mean into Am ----
    {
        const int lane = t & 15, nd = t >> 4;   // 16 nodes per pass
        const unsigned short* gbase = src + lane * 8;
#pragma unroll 1
        for (int p = 0; p < 8; p++) {
            int nl = p * 16 + nd;               // 0..127 local row
            int node = row0 + nl;
            float a[8];
#pragma unroll
            for (int j = 0; j < 8; j++) a[j] = 0.f;
            int n = 0;
            if (node < N_NODES) {
                int beg = row_start[node];
                int end = row_start[node + 1];
                n = end - beg;
                if (n > 0) {
                    int nm1 = n - 1;
                    int s[16];
#pragma unroll
                    for (int j = 0; j < 16; j++) {
                        int jj = (j < nm1) ? j : nm1;   // clamp into [beg,end-1]
                        s[j] = csr_src[beg + jj];
                    }
                    uint4 u[16];
#pragma unroll
                    for (int j = 0; j < 16; j++)
                        u[j] = *(const uint4*)(gbase + (size_t)s[j] * CH);
#pragma unroll
                    for (int j = 0; j < 16; j++) {
                        if (j < n) {
                            acc_u32(u[j].x, a[0], a[1]); acc_u32(u[j].y, a[2], a[3]);
                            acc_u32(u[j].z, a[4], a[5]); acc_u32(u[j].w, a[6], a[7]);
                        }
                    }
                    int e = beg + 16;
                    while (e + 8 <= end) {
                        int s2[8];
#pragma unroll
                        for (int j = 0; j < 8; j++) s2[j] = csr_src[e + j];
                        uint4 u2[8];
#pragma unroll
                        for (int j = 0; j < 8; j++)
                            u2[j] = *(const uint4*)(gbase + (size_t)s2[j] * CH);
#pragma unroll
                        for (int j = 0; j < 8; j++) {
                            acc_u32(u2[j].x, a[0], a[1]); acc_u32(u2[j].y, a[2], a[3]);
                            acc_u32(u2[j].z, a[4], a[5]); acc_u32(u2[j].w, a[6], a[7]);
                        }
                        e += 8;
                    }
                    while (e < end) {
                        int s0 = csr_src[e];
                        uint4 u0 = *(const uint4*)(gbase + (size_t)s0 * CH);
                        acc_u32(u0.x, a[0], a[1]); acc_u32(u0.y, a[2], a[3]);
                        acc_u32(u0.z, a[4], a[5]); acc_u32(u0.w, a[6], a[7]);
                        e++;
                    }
                }
            }
            float rinv = 1.0f / (float)max(n, 1);
            unsigned int p0 = (unsigned int)f2bf(a[0] * rinv) | ((unsigned int)f2bf(a[1] * rinv) << 16);
            unsigned int p1 = (unsigned int)f2bf(a[2] * rinv) | ((unsigned int)f2bf(a[3] * rinv) << 16);
            unsigned int p2 = (unsigned int)f2bf(a[4] * rinv) | ((unsigned int)f2bf(a[5] * rinv) << 16);
            unsigned int p3 = (unsigned int)f2bf(a[6] * rinv) | ((unsigned int)f2bf(a[7] * rinv) << 16);
            *(uint4*)&Am[nl * LDA + lane * 8] = make_uint4(p0, p1, p2, p3);
        }
    }

    // ---- phase 2: MFMA K-loop ----
    int ar = row0 + srow;
    if (ar >= N_NODES) ar = N_NODES - 1;
    const unsigned short* abase = src + (size_t)ar * CH + shalf * 16;  // root half
    const unsigned short* bbase = WT + (size_t)srow * KTOT + shalf * 16;

    v4f acc[4][4];
#pragma unroll
    for (int i = 0; i < 4; i++)
#pragma unroll
        for (int j = 0; j < 4; j++) acc[i][j] = (v4f){0.f, 0.f, 0.f, 0.f};

    {   // prologue: stage B step 0
        uint4 b0 = *(const uint4*)bbase, b1 = *(const uint4*)(bbase + 8);
        *(uint4*)&Bs[srow * LDK + shalf * 16] = b0;
        *(uint4*)&Bs[srow * LDK + shalf * 16 + 8] = b1;
    }
#pragma unroll
    for (int k = 0; k < KTOT / 32; k++) {
        uint4 na0, na1, nb0, nb1;
        if (k < KTOT / 32 - 1) {
            nb0 = *(const uint4*)(bbase + (k + 1) * 32);
            nb1 = *(const uint4*)(bbase + (k + 1) * 32 + 8);
            if (k >= 3) {   // stage root rows for steps 4..7 (src col (k+1-4)*32)
                na0 = *(const uint4*)(abase + (k - 3) * 32);
                na1 = *(const uint4*)(abase + (k - 3) * 32 + 8);
            }
        }
        __syncthreads();
        const int cur = (k & 1) * 128 * LDK, nxt = ((k + 1) & 1) * 128 * LDK;
        v8s af[4], bfr[4];
        if (k < 4) {
#pragma unroll
            for (int mi = 0; mi < 4; mi++)
                af[mi] = *(const v8s*)&Am[(wy * 64 + mi * 16 + lrow) * LDA +
                                          k * 32 + quad * 8];
        } else {
#pragma unroll
            for (int mi = 0; mi < 4; mi++)
                af[mi] = *(const v8s*)&As[cur + (wy * 64 + mi * 16 + lrow) * LDK +
                                          quad * 8];
        }
#pragma unroll
        for (int ni = 0; ni < 4; ni++)
            bfr[ni] = *(const v8s*)&Bs[cur + (wx * 64 + ni * 16 + lrow) * LDK + quad * 8];
#pragma unroll
        for (int mi = 0; mi < 4; mi++)
#pragma unroll
            for (int ni = 0; ni < 4; ni++)
                acc[mi][ni] = __builtin_amdgcn_mfma_f32_16x16x32_bf16(
                    af[mi], bfr[ni], acc[mi][ni], 0, 0, 0);
        if (k < KTOT / 32 - 1) {
            *(uint4*)&Bs[nxt + srow * LDK + shalf * 16] = nb0;
            *(uint4*)&Bs[nxt + srow * LDK + shalf * 16 + 8] = nb1;
            if (k >= 3) {
                *(uint4*)&As[nxt + srow * LDK + shalf * 16] = na0;
                *(uint4*)&As[nxt + srow * LDK + shalf * 16 + 8] = na1;
            }
        }
    }
    float bj[4];
#pragma unroll
    for (int ni = 0; ni < 4; ni++) bj[ni] = ldf(bias, isbf, wx * 64 + ni * 16 + lrow);

    if (!cls_out) {
#pragma unroll
        for (int mi = 0; mi < 4; mi++) {
#pragma unroll
            for (int r = 0; r < 4; r++) {
                int grow = row0 + wy * 64 + mi * 16 + quad * 4 + r;
                if (grow < N_NODES) {
#pragma unroll
                    for (int ni = 0; ni < 4; ni++) {
                        int col = wx * 64 + ni * 16 + lrow;
                        float v = fmaxf(acc[mi][ni][r] + bj[ni], 0.0f);
                        out[(size_t)grow * CH + col] = f2bf(v);
                    }
                }
            }
        }
    } else {
        __syncthreads();
#pragma unroll
        for (int mi = 0; mi < 4; mi++) {
#pragma unroll
            for (int r = 0; r < 4; r++) {
                int row = wy * 64 + mi * 16 + quad * 4 + r;
#pragma unroll
                for (int ni = 0; ni < 4; ni++) {
                    int col = wx * 64 + ni * 16 + lrow;
                    float v = fmaxf(acc[mi][ni][r] + bj[ni], 0.0f);
                    smem[row * CLS_LD + col] = f2bf(v);
                }
            }
        }
        __syncthreads();
        if (t < 128) {
            int grow = row0 + t;
            if (grow < N_NODES) {
                float a0 = 0.f, a1 = 0.f, a2 = 0.f;
                for (int k = 0; k < CH; k++) {
                    float h = bf2f(smem[t * CLS_LD + k]);
                    a0 += h * wcls_s[k * NCLS + 0];
                    a1 += h * wcls_s[k * NCLS + 1];
                    a2 += h * wcls_s[k * NCLS + 2];
                }
                cls_out[(size_t)grow * NCLS + 0] = a0 + ldf(bcls, isbf, 0);
                cls_out[(size_t)grow * NCLS + 1] = a1 + ldf(bcls, isbf, 1);
                cls_out[(size_t)grow * NCLS + 2] = a2 + ldf(bcls, isbf, 2);
            }
        }
    }
}

extern "C" void kernel_launch(void* const* d_in, const int* in_sizes, int n_in,
                              void* d_out, int out_size, void* d_ws, size_t ws_size,
                              hipStream_t stream) {
    const void* x = d_in[0];
    const void* eidx = d_in[1];
    const void* w_l1 = d_in[2];
    const void* b_l1 = d_in[3];
    const void* w_r1 = d_in[4];
    const void* w_l2 = d_in[5];
    const void* b_l2 = d_in[6];
    const void* w_r2 = d_in[7];
    const void* w_cls = d_in[8];
    const void* b_cls = d_in[9];

    char* w = (char*)d_ws;
    int* eflag = (int*)w;
    int* dtf = (int*)(w + 64);
    int* done = (int*)(w + 128);
    int* hist = (int*)(w + 4096);                            // 192,080 B
    int* bsum = (int*)(w + 196608);                          // 188 B
    int* row_start = (int*)(w + 262144);                     // 400,004 B
    unsigned int* part = (unsigned int*)(w + 720896);        // 4 MB
    int* csr_src = (int*)(w + 4915200);                      // 4 MB
    unsigned short* WT1 = (unsigned short*)(w + 8978432);    // 64 KB
    unsigned short* WT2 = (unsigned short*)(w + 9043968);    // 64 KB
    unsigned short* Xb = (unsigned short*)(w + 11534336);    // 25.6 MB  [N][128] x bf16
    unsigned short* Hb = (unsigned short*)(w + 62914560);    // 25.6 MB  [N][128] h1 bf16

    hipLaunchKernelGGL(k_init, dim3(2), dim3(256), 0, stream,
                       eidx, (const unsigned int*)x, eflag, dtf, done);
    hipLaunchKernelGGL(k_A1, dim3(NB_A1), dim3(256), 0, stream,
                       eidx, eflag, dtf, hist, x, Xb,
                       w_l1, w_r1, WT1, w_l2, w_r2, WT2);
    hipLaunchKernelGGL(k_scanH, dim3(NB_SCAN), dim3(1024), 0, stream,
                       hist, bsum, done);
    hipLaunchKernelGGL(k_A3, dim3(NB_A), dim3(256), 0, stream,
                       eidx, eflag, hist, part);
    hipLaunchKernelGGL(k_B, dim3(NBKT), dim3(1024), 0, stream,
                       hist, part, row_start, csr_src);
    // layer 1 (fused gather-mean + GEMM): Xb -> Hb
    hipLaunchKernelGGL(k_gemm_fused, dim3((N_NODES + 127) / 128), dim3(256), 0, stream,
                       row_start, csr_src, Xb, WT1, b_l1, dtf, Hb,
                       (const void*)nullptr, (const void*)nullptr, (float*)nullptr);
    // layer 2 (fused) + classifier: Hb -> logits
    hipLaunchKernelGGL(k_gemm_fused, dim3((N_NODES + 127) / 128), dim3(256), 0, stream,
                       row_start, csr_src, Hb, WT2, b_l2, dtf,
                       (unsigned short*)nullptr, w_cls, b_cls, (float*)d_out);
}

// Round 4
// 256.130 us; speedup vs baseline: 1.0917x; 1.0917x over previous
//
#include <hip/hip_runtime.h>
#include <hip/hip_bf16.h>

#define N_NODES 100000
#define N_EDGES 1000000
#define CH 128
#define KTOT 256
#define NCLS 3

#define NBKT 196                    // coarse buckets: dst>>9
#define EPB 4096                    // edges per partition block (parallelism!)
#define NB_A ((N_EDGES + EPB - 1) / EPB)          // 245
#define M_H (NBKT * NB_A)                          // 48020
#define NB_SCAN ((M_H + 1023) / 1024)              // 47 co-resident blocks

#define NB_CVTX (N_NODES * CH / 4 / 256)           // 12500
#define NB_CVTW (KTOT * CH / 256)                  // 128
#define NB_A1 (NB_A + NB_CVTX + 2 * NB_CVTW)       // 13001

typedef __attribute__((ext_vector_type(8))) short v8s;   // 8 bf16 (A/B frag)
typedef __attribute__((ext_vector_type(4))) float v4f;   // 4 f32 (C/D frag)

__device__ __forceinline__ float bf2f(unsigned short u) {
    return __uint_as_float(((unsigned int)u) << 16);
}

__device__ __forceinline__ unsigned short f2bf(float f) {  // RNE
    unsigned int u = __float_as_uint(f);
    unsigned int r = (u + 0x7fffu + ((u >> 16) & 1u)) >> 16;
    return (unsigned short)r;
}

__device__ __forceinline__ int edge_at(const void* e, int is64, long long i) {
    if (is64) return (int)((const long long*)e)[i];
    return ((const int*)e)[i];
}

__device__ __forceinline__ float ldf(const void* p, int isbf, size_t i) {
    if (isbf) return bf2f(((const unsigned short*)p)[i]);
    return ((const float*)p)[i];
}

__device__ __forceinline__ void acc_u32(unsigned int u, float& a0, float& a1) {
    a0 += bf2f((unsigned short)(u & 0xffffu));
    a1 += bf2f((unsigned short)(u >> 16));
}

// --- K0: dtype sniffers + done flag ---
__global__ void k_init(const void* __restrict__ e, const unsigned int* __restrict__ x,
                       int* __restrict__ eflag, int* __restrict__ dtf,
                       int* __restrict__ done) {
    if (blockIdx.x == 0) {
        if (threadIdx.x < 64) {
            int v = ((const int*)e)[2 * threadIdx.x + 1];
            unsigned long long bl = __ballot(v != 0);
            if (threadIdx.x == 0) *eflag = (bl == 0ULL) ? 1 : 0;
        } else if (threadIdx.x == 64) {
            *done = 0;
        }
    } else {
        if (threadIdx.x < 64) {
            unsigned int u = x[threadIdx.x];
            int ex = (u >> 7) & 0xff;
            int sane = (ex == 0) || (ex >= 100 && ex <= 154);
            unsigned long long bl = __ballot(sane);
            if (threadIdx.x == 0) *dtf = (__popcll(bl) >= 48) ? 1 : 0;
        }
    }
}

// --- K1: coarse-bucket histogram (LDS atomics only) interleaved with cvt.
// x converts to a DENSE [N][128] bf16 buffer (halved gather footprint =>
// L2 aggregate 32MB now covers the 25.6MB source). ---
__global__ void k_A1(const void* __restrict__ e, const int* __restrict__ eflag,
                     const int* __restrict__ dtf, int* __restrict__ hist,
                     const void* __restrict__ x, unsigned short* __restrict__ Xb,
                     const void* __restrict__ wl1, const void* __restrict__ wr1,
                     unsigned short* __restrict__ WT1,
                     const void* __restrict__ wl2, const void* __restrict__ wr2,
                     unsigned short* __restrict__ WT2) {
    int b = blockIdx.x;
    int t = threadIdx.x;
    if (b < NB_A) {
        __shared__ int h[NBKT];
        if (t < NBKT) h[t] = 0;
        __syncthreads();
        int is64 = *eflag;
#pragma unroll
        for (int j = 0; j < EPB / 256; j++) {
            int i = b * EPB + j * 256 + t;
            if (i < N_EDGES) {
                int dst = edge_at(e, is64, (long long)N_EDGES + i);
                atomicAdd(&h[dst >> 9], 1);
            }
        }
        __syncthreads();
        if (t < NBKT) hist[t * NB_A + b] = h[t];
    } else {
        int ob = b - NB_A;
        if (ob < NB_CVTX) {
            int idx = ob * 256 + t;
            int node = idx >> 5;
            int ch = (idx & 31) * 4;
            int isbf = *dtf;
            unsigned short o[4];
            if (isbf) {
                ushort4 u = *(const ushort4*)((const unsigned short*)x +
                                              (size_t)node * CH + ch);
                o[0] = u.x; o[1] = u.y; o[2] = u.z; o[3] = u.w;
            } else {
                float4 v = *(const float4*)((const float*)x + (size_t)node * CH + ch);
                o[0] = f2bf(v.x); o[1] = f2bf(v.y); o[2] = f2bf(v.z); o[3] = f2bf(v.w);
            }
            *(ushort4*)(Xb + (size_t)node * CH + ch) =
                make_ushort4(o[0], o[1], o[2], o[3]);
        } else {
            int rel = ob - NB_CVTX;
            const void* wl = (rel < NB_CVTW) ? wl1 : wl2;
            const void* wr = (rel < NB_CVTW) ? wr1 : wr2;
            unsigned short* WT = (rel < NB_CVTW) ? WT1 : WT2;
            int i = (rel % NB_CVTW) * 256 + t;
            int k = i >> 7;
            int n = i & 127;
            int isbf = *dtf;
            float v = (k < CH) ? ldf(wl, isbf, (size_t)k * CH + n)
                               : ldf(wr, isbf, (size_t)(k - CH) * CH + n);
            WT[(size_t)n * KTOT + k] = f2bf(v);
        }
    }
}

// --- K2: multi-block exclusive scan, producer-only spin barrier ---
__global__ __launch_bounds__(1024) void k_scanH(int* __restrict__ hist,
                                                int* __restrict__ bsum,
                                                int* __restrict__ done) {
    __shared__ int s[1024];
    __shared__ int pre_sh;
    int t = threadIdx.x, b = blockIdx.x;
    int idx = b * 1024 + t;
    int v = (idx < M_H) ? hist[idx] : 0;
    s[t] = v;
    __syncthreads();
    for (int off = 1; off < 1024; off <<= 1) {
        int u = (t >= off) ? s[t - off] : 0;
        __syncthreads();
        s[t] += u;
        __syncthreads();
    }
    if (t == 1023) {
        bsum[b] = s[t];
        __threadfence();
        atomicAdd(done, 1);
    }
    if (t == 0) {
        while (__hip_atomic_load(done, __ATOMIC_ACQUIRE,
                                 __HIP_MEMORY_SCOPE_AGENT) < NB_SCAN) {
        }
        __threadfence();
        int run = 0;
        for (int r = 0; r < b; r++) run += bsum[r];
        pre_sh = run;
    }
    __syncthreads();
    if (idx < M_H) hist[idx] = s[t] - v + pre_sh;  // exclusive
}

// --- K3: partition scatter via LDS cursors; pack (src<<9)|(dst&511) ---
__global__ void k_A3(const void* __restrict__ e, const int* __restrict__ eflag,
                     const int* __restrict__ hist, unsigned int* __restrict__ part) {
    __shared__ int cur[NBKT];
    int b = blockIdx.x;
    int t = threadIdx.x;
    if (t < NBKT) cur[t] = hist[t * NB_A + b];
    __syncthreads();
    int is64 = *eflag;
#pragma unroll
    for (int j = 0; j < EPB / 256; j++) {
        int i = b * EPB + j * 256 + t;
        if (i < N_EDGES) {
            int src = edge_at(e, is64, i);
            int dst = edge_at(e, is64, (long long)N_EDGES + i);
            int pos = atomicAdd(&cur[dst >> 9], 1);  // LDS atomic
            part[pos] = ((unsigned int)src << 9) | (unsigned int)(dst & 511);
        }
    }
}

// --- K4: per-bucket finalize: degree count + scan -> row_start + csr_src ---
__global__ __launch_bounds__(1024) void k_B(const int* __restrict__ hist,
                                            const unsigned int* __restrict__ part,
                                            int* __restrict__ row_start,
                                            int* __restrict__ csr_src) {
    __shared__ int dcnt[512], sa[512], curs[512];
    int b = blockIdx.x;
    int t = threadIdx.x;
    int e0 = hist[b * NB_A];
    int e1 = (b + 1 < NBKT) ? hist[(b + 1) * NB_A] : N_EDGES;
    if (t < 512) dcnt[t] = 0;
    __syncthreads();
    for (int i = e0 + t; i < e1; i += 1024)
        atomicAdd(&dcnt[part[i] & 511], 1);
    __syncthreads();
    if (t < 512) sa[t] = dcnt[t];
    __syncthreads();
    for (int off = 1; off < 512; off <<= 1) {
        int v = 0;
        if (t < 512 && t >= off) v = sa[t - off];
        __syncthreads();
        if (t < 512) sa[t] += v;
        __syncthreads();
    }
    if (t < 512) {
        int excl = sa[t] - dcnt[t];
        curs[t] = e0 + excl;
        int node = b * 512 + t;
        if (node < N_NODES) row_start[node] = e0 + excl;
    }
    if (b == 0 && t == 0) row_start[N_NODES] = N_EDGES;
    __syncthreads();
    for (int i = e0 + t; i < e1; i += 1024) {
        unsigned int p = part[i];
        int pos = atomicAdd(&curs[p & 511], 1);  // LDS atomic
        csr_src[pos] = (int)(p >> 9);
    }
}

// --- gather-mean: 4 nodes/wave, 16 lanes/node, dense [N][128] src -> dense
// mean buffer. 16-deep clamped batch (P(deg<=16)=97%), 8/1 tails. ---
__global__ __launch_bounds__(256) void k_agg(
    const int* __restrict__ row_start, const int* __restrict__ csr_src,
    const unsigned short* __restrict__ src, unsigned short* __restrict__ mdst) {
    long long gt = (long long)blockIdx.x * blockDim.x + threadIdx.x;
    int node = (int)(gt >> 4);
    int lane = (int)(gt & 15);
    if (node >= N_NODES) return;
    int beg = row_start[node];
    int end = row_start[node + 1];
    int n = end - beg;
    float a[8];
#pragma unroll
    for (int j = 0; j < 8; j++) a[j] = 0.f;
    if (n > 0) {
        const unsigned short* gbase = src + lane * 8;
        int nm1 = n - 1;
        int s[16];
#pragma unroll
        for (int j = 0; j < 16; j++) {
            int jj = (j < nm1) ? j : nm1;          // clamp: always in [beg,end-1]
            s[j] = csr_src[beg + jj];
        }
        uint4 u[16];
#pragma unroll
        for (int j = 0; j < 16; j++)
            u[j] = *(const uint4*)(gbase + (size_t)s[j] * CH);
#pragma unroll
        for (int j = 0; j < 16; j++) {
            if (j < n) {                            // mask dup tail
                acc_u32(u[j].x, a[0], a[1]); acc_u32(u[j].y, a[2], a[3]);
                acc_u32(u[j].z, a[4], a[5]); acc_u32(u[j].w, a[6], a[7]);
            }
        }
        int e = beg + 16;
        while (e + 8 <= end) {
            int s2[8];
#pragma unroll
            for (int j = 0; j < 8; j++) s2[j] = csr_src[e + j];
            uint4 u2[8];
#pragma unroll
            for (int j = 0; j < 8; j++)
                u2[j] = *(const uint4*)(gbase + (size_t)s2[j] * CH);
#pragma unroll
            for (int j = 0; j < 8; j++) {
                acc_u32(u2[j].x, a[0], a[1]); acc_u32(u2[j].y, a[2], a[3]);
                acc_u32(u2[j].z, a[4], a[5]); acc_u32(u2[j].w, a[6], a[7]);
            }
            e += 8;
        }
        while (e < end) {
            int s0 = csr_src[e];
            uint4 u0 = *(const uint4*)(gbase + (size_t)s0 * CH);
            acc_u32(u0.x, a[0], a[1]); acc_u32(u0.y, a[2], a[3]);
            acc_u32(u0.z, a[4], a[5]); acc_u32(u0.w, a[6], a[7]);
            e++;
        }
    }
    float rinv = 1.0f / (float)max(n, 1);
    unsigned int p0 = (unsigned int)f2bf(a[0] * rinv) | ((unsigned int)f2bf(a[1] * rinv) << 16);
    unsigned int p1 = (unsigned int)f2bf(a[2] * rinv) | ((unsigned int)f2bf(a[3] * rinv) << 16);
    unsigned int p2 = (unsigned int)f2bf(a[4] * rinv) | ((unsigned int)f2bf(a[5] * rinv) << 16);
    unsigned int p3 = (unsigned int)f2bf(a[6] * rinv) | ((unsigned int)f2bf(a[7] * rinv) << 16);
    *(uint4*)(mdst + (size_t)node * CH + lane * 8) = make_uint4(p0, p1, p2, p3);
}

// --- MFMA GEMM, double-buffered; A operand = Mb (k=0..3) ++ Xroot (k=4..7);
// optional fused classifier epilogue (wcls loaded into reused smem at
// epilogue time so main-loop LDS stays 40KB -> 4 blocks/CU). ---
#define LDK 40
#define CLS_LD 130
__global__ __launch_bounds__(256) void k_gemm_mfma(
    const unsigned short* __restrict__ Mb,     // [N][CH] mean, bf16
    const unsigned short* __restrict__ Xr,     // [N][CH] root, bf16
    const unsigned short* __restrict__ WT, const void* __restrict__ bias,
    const int* __restrict__ dtf,
    unsigned short* __restrict__ out,          // [N][CH] bf16 or null
    const void* __restrict__ wcls, const void* __restrict__ bcls,
    float* __restrict__ cls_out) {
    __shared__ unsigned short smem[4 * 128 * LDK];   // As dbuf + Bs dbuf (40KB)
    unsigned short* As = smem;
    unsigned short* Bs = smem + 2 * 128 * LDK;
    const int t = threadIdx.x;
    const int w = t >> 6, l = t & 63;
    const int wx = w & 1, wy = w >> 1;
    const int quad = l >> 4, lrow = l & 15;
    const int row0 = blockIdx.x * 128;
    const int srow = t >> 1, shalf = t & 1;
    const int isbf = *dtf;

    int ar = row0 + srow;
    if (ar >= N_NODES) ar = N_NODES - 1;
    const unsigned short* abase_m = Mb + (size_t)ar * CH + shalf * 16;
    const unsigned short* abase_x = Xr + (size_t)ar * CH + shalf * 16;
    const unsigned short* bbase = WT + (size_t)srow * KTOT + shalf * 16;

    v4f acc[4][4];
#pragma unroll
    for (int i = 0; i < 4; i++)
#pragma unroll
        for (int j = 0; j < 4; j++) acc[i][j] = (v4f){0.f, 0.f, 0.f, 0.f};

    {   // prologue: stage step 0 (A from mean)
        uint4 a0 = *(const uint4*)abase_m, a1 = *(const uint4*)(abase_m + 8);
        uint4 b0 = *(const uint4*)bbase, b1 = *(const uint4*)(bbase + 8);
        *(uint4*)&As[srow * LDK + shalf * 16] = a0;
        *(uint4*)&As[srow * LDK + shalf * 16 + 8] = a1;
        *(uint4*)&Bs[srow * LDK + shalf * 16] = b0;
        *(uint4*)&Bs[srow * LDK + shalf * 16 + 8] = b1;
    }
#pragma unroll
    for (int k = 0; k < KTOT / 32; k++) {
        uint4 na0, na1, nb0, nb1;
        if (k < KTOT / 32 - 1) {
            const unsigned short* na = (k < 3) ? (abase_m + (k + 1) * 32)
                                               : (abase_x + (k - 3) * 32);
            na0 = *(const uint4*)na;
            na1 = *(const uint4*)(na + 8);
            nb0 = *(const uint4*)(bbase + (k + 1) * 32);
            nb1 = *(const uint4*)(bbase + (k + 1) * 32 + 8);
        }
        __syncthreads();
        const int cur = (k & 1) * 128 * LDK, nxt = ((k + 1) & 1) * 128 * LDK;
        v8s af[4], bfr[4];
#pragma unroll
        for (int mi = 0; mi < 4; mi++)
            af[mi] = *(const v8s*)&As[cur + (wy * 64 + mi * 16 + lrow) * LDK + quad * 8];
#pragma unroll
        for (int ni = 0; ni < 4; ni++)
            bfr[ni] = *(const v8s*)&Bs[cur + (wx * 64 + ni * 16 + lrow) * LDK + quad * 8];
#pragma unroll
        for (int mi = 0; mi < 4; mi++)
#pragma unroll
            for (int ni = 0; ni < 4; ni++)
                acc[mi][ni] = __builtin_amdgcn_mfma_f32_16x16x32_bf16(
                    af[mi], bfr[ni], acc[mi][ni], 0, 0, 0);
        if (k < KTOT / 32 - 1) {
            *(uint4*)&As[nxt + srow * LDK + shalf * 16] = na0;
            *(uint4*)&As[nxt + srow * LDK + shalf * 16 + 8] = na1;
            *(uint4*)&Bs[nxt + srow * LDK + shalf * 16] = nb0;
            *(uint4*)&Bs[nxt + srow * LDK + shalf * 16 + 8] = nb1;
        }
    }
    float bj[4];
#pragma unroll
    for (int ni = 0; ni < 4; ni++) bj[ni] = ldf(bias, isbf, wx * 64 + ni * 16 + lrow);

    if (!cls_out) {
#pragma unroll
        for (int mi = 0; mi < 4; mi++) {
#pragma unroll
            for (int r = 0; r < 4; r++) {
                int grow = row0 + wy * 64 + mi * 16 + quad * 4 + r;
                if (grow < N_NODES) {
#pragma unroll
                    for (int ni = 0; ni < 4; ni++) {
                        int col = wx * 64 + ni * 16 + lrow;
                        float v = fmaxf(acc[mi][ni][r] + bj[ni], 0.0f);
                        out[(size_t)grow * CH + col] = f2bf(v);
                    }
                }
            }
        }
    } else {
        __syncthreads();   // all waves done with As/Bs -> reuse smem
        float* wcls_s = (float*)(smem + 16896);  // 384 floats @ byte 33792 (<40KB)
        for (int i = t; i < CH * NCLS; i += 256) wcls_s[i] = ldf(wcls, isbf, i);
#pragma unroll
        for (int mi = 0; mi < 4; mi++) {
#pragma unroll
            for (int r = 0; r < 4; r++) {
                int row = wy * 64 + mi * 16 + quad * 4 + r;
#pragma unroll
                for (int ni = 0; ni < 4; ni++) {
                    int col = wx * 64 + ni * 16 + lrow;
                    float v = fmaxf(acc[mi][ni][r] + bj[ni], 0.0f);
                    smem[row * CLS_LD + col] = f2bf(v);
                }
            }
        }
        __syncthreads();
        if (t < 128) {
            int grow = row0 + t;
            if (grow < N_NODES) {
                float a0 = 0.f, a1 = 0.f, a2 = 0.f;
                for (int k = 0; k < CH; k++) {
                    float h = bf2f(smem[t * CLS_LD + k]);
                    a0 += h * wcls_s[k * NCLS + 0];
                    a1 += h * wcls_s[k * NCLS + 1];
                    a2 += h * wcls_s[k * NCLS + 2];
                }
                cls_out[(size_t)grow * NCLS + 0] = a0 + ldf(bcls, isbf, 0);
                cls_out[(size_t)grow * NCLS + 1] = a1 + ldf(bcls, isbf, 1);
                cls_out[(size_t)grow * NCLS + 2] = a2 + ldf(bcls, isbf, 2);
            }
        }
    }
}

extern "C" void kernel_launch(void* const* d_in, const int* in_sizes, int n_in,
                              void* d_out, int out_size, void* d_ws, size_t ws_size,
                              hipStream_t stream) {
    const void* x = d_in[0];
    const void* eidx = d_in[1];
    const void* w_l1 = d_in[2];
    const void* b_l1 = d_in[3];
    const void* w_r1 = d_in[4];
    const void* w_l2 = d_in[5];
    const void* b_l2 = d_in[6];
    const void* w_r2 = d_in[7];
    const void* w_cls = d_in[8];
    const void* b_cls = d_in[9];

    char* w = (char*)d_ws;
    int* eflag = (int*)w;
    int* dtf = (int*)(w + 64);
    int* done = (int*)(w + 128);
    int* hist = (int*)(w + 4096);                            // 192,080 B
    int* bsum = (int*)(w + 196608);                          // 188 B
    int* row_start = (int*)(w + 262144);                     // 400,004 B
    unsigned int* part = (unsigned int*)(w + 720896);        // 4 MB
    int* csr_src = (int*)(w + 4915200);                      // 4 MB
    unsigned short* WT1 = (unsigned short*)(w + 8978432);    // 64 KB
    unsigned short* WT2 = (unsigned short*)(w + 9043968);    // 64 KB
    unsigned short* Xb = (unsigned short*)(w + 11534336);    // 25.6 MB, ends 37,134,336
    unsigned short* Mb = (unsigned short*)(w + 37748736);    // 25.6 MB, ends 63,348,736
    unsigned short* Hb = (unsigned short*)(w + 67108864);    // 25.6 MB, ends 92,708,864
    // (r3 bug: Hb at 62,914,560 overlapped Mb's tail by 434KB -> race. Fixed:
    // all three dense buffers disjoint, all within proven 114.1 MB extent.)

    hipLaunchKernelGGL(k_init, dim3(2), dim3(256), 0, stream,
                       eidx, (const unsigned int*)x, eflag, dtf, done);
    hipLaunchKernelGGL(k_A1, dim3(NB_A1), dim3(256), 0, stream,
                       eidx, eflag, dtf, hist, x, Xb,
                       w_l1, w_r1, WT1, w_l2, w_r2, WT2);
    hipLaunchKernelGGL(k_scanH, dim3(NB_SCAN), dim3(1024), 0, stream,
                       hist, bsum, done);
    hipLaunchKernelGGL(k_A3, dim3(NB_A), dim3(256), 0, stream,
                       eidx, eflag, hist, part);
    hipLaunchKernelGGL(k_B, dim3(NBKT), dim3(1024), 0, stream,
                       hist, part, row_start, csr_src);
    // layer 1: gather Xb -> Mb, then GEMM (Mb ++ Xb) -> Hb
    hipLaunchKernelGGL(k_agg, dim3(N_NODES * 16 / 256), dim3(256), 0, stream,
                       row_start, csr_src, Xb, Mb);
    hipLaunchKernelGGL(k_gemm_mfma, dim3((N_NODES + 127) / 128), dim3(256), 0, stream,
                       Mb, Xb, WT1, b_l1, dtf, Hb,
                       (const void*)nullptr, (const void*)nullptr, (float*)nullptr);
    // layer 2: gather Hb -> Mb, then GEMM (Mb ++ Hb) + classifier -> logits
    hipLaunchKernelGGL(k_agg, dim3(N_NODES * 16 / 256), dim3(256), 0, stream,
                       row_start, csr_src, Hb, Mb);
    hipLaunchKernelGGL(k_gemm_mfma, dim3((N_NODES + 127) / 128), dim3(256), 0, stream,
                       Mb, Hb, WT2, b_l2, dtf, (unsigned short*)nullptr,
                       w_cls, b_cls, (float*)d_out);
}